// Round 10
// baseline (37.187 us; speedup 1.0000x reference)
//
#include <hip/hip_runtime.h>
#include <hip/hip_fp16.h>

// B=32, L=512, N=128, IN=16, OUT=10
// Two kernels, one boundary:
//  K1 (8 chunks x 32 b, 512 thr): micro-MLP for 64 leaves in LDS (computed
//     once, never hits global), f16-packed bitmask max-agg over those leaves
//     for all 128 nodes -> pagg[b][node][chunk][pair].
//  K2 (32 blocks, one per b): combine 8 chunk-partials, f_macro, W4 dot ->
//     y[b]; 32-block arrival (threadfence+atomicAdd); last block does
//     BatchNorm (batch stats) + @W5+b5 -> out.

// ROCm 7.2 headers lack a gfx950-viable __hmax2; emit the instruction directly.
static __device__ __forceinline__ unsigned pk_max_f16(unsigned a, unsigned b) {
    unsigned r;
    asm("v_pk_max_f16 %0, %1, %2" : "=v"(r) : "v"(a), "v"(b));
    return r;
}

__global__ __launch_bounds__(512, 2) void k_fused1(
    const float* __restrict__ x, const float* __restrict__ tree,
    const float* __restrict__ W1, const float* __restrict__ b1,
    const float* __restrict__ W2, const float* __restrict__ b2,
    unsigned* __restrict__ pagg, unsigned* __restrict__ counter)
{
    const int chunk = blockIdx.x;   // 0..7  (leaves chunk*64..+63)
    const int b     = blockIdx.y;   // 0..31
    const int tid   = threadIdx.x;

    if (chunk == 0 && b == 0 && tid == 0) *counter = 0u;   // consumed by K2

    __shared__ float    sx[1024];    // [64][16] x chunk
    __shared__ float    sW1[512];    // [16][32]
    __shared__ float    sW2[2048];   // [32][64]
    __shared__ float    sb1[32];
    __shared__ float    sb2[64];
    __shared__ float    sh1[2048];   // [64][32] layer-1 out
    __shared__ unsigned sh16[2048];  // [64][32] h as f16x2
    __shared__ unsigned smask[256];  // [64][4]  node-bit words per leaf

    // ---- stage x chunk + weights ----
    sx[tid]       = x[(size_t)b * 8192 + chunk * 1024 + tid];
    sx[tid + 512] = x[(size_t)b * 8192 + chunk * 1024 + 512 + tid];
    sW1[tid & 511] = W1[tid & 511];          // all 512 threads, once
    sW2[tid]        = W2[tid];
    sW2[tid + 512]  = W2[tid + 512];
    sW2[tid + 1024] = W2[tid + 1024];
    sW2[tid + 1536] = W2[tid + 1536];
    if (tid < 32) sb1[tid] = b1[tid];
    if (tid < 64) sb2[tid] = b2[tid];

    // ---- node-bit masks: leaf = tid>>2, word = tid&3 (nodes word*32..+31)
    if (tid < 256) {
        const int leaf = tid >> 2, word = tid & 3;
        const float* tp = tree + (size_t)(word * 32) * 512 + chunk * 64 + leaf;
        unsigned bits = 0;
        #pragma unroll
        for (int k = 0; k < 32; ++k)
            if (tp[(size_t)k * 512] > 0.5f) bits |= (1u << k);
        smask[leaf * 4 + word] = bits;
    }
    __syncthreads();

    // ---- layer1: c = tid&31, rows (tid>>5)*4..+3 ----
    {
        const int c = tid & 31, rg = tid >> 5;
        #pragma unroll
        for (int rr = 0; rr < 4; ++rr) {
            const int row = rg * 4 + rr;
            float a = sb1[c];
            #pragma unroll
            for (int i = 0; i < 16; ++i) a += sx[row * 16 + i] * sW1[i * 32 + c];
            sh1[row * 32 + c] = fmaxf(a, 0.f);
        }
    }
    __syncthreads();

    // ---- layer2 + f16 pack: pair p = tid&31, rows (tid>>5)*4..+3 ----
    {
        const int p = tid & 31, rg = tid >> 5;
        #pragma unroll
        for (int rr = 0; rr < 4; ++rr) {
            const int row = rg * 4 + rr;
            float a0 = sb2[2 * p], a1 = sb2[2 * p + 1];
            #pragma unroll
            for (int j = 0; j < 32; ++j) {
                const float v = sh1[row * 32 + j];            // broadcast
                const float2 w = *(const float2*)&sW2[j * 64 + 2 * p];
                a0 += v * w.x; a1 += v * w.y;
            }
            __half2 hp = __floats2half2_rn(fmaxf(a0, 0.f), fmaxf(a1, 0.f));
            sh16[row * 32 + p] = *(unsigned*)&hp;
        }
    }
    __syncthreads();

    // ---- agg: node-octet o = tid>>5 (0..15), pair p = tid&31 ----
    // thread-private (o,p): no barriers, no shuffles.
    {
        const int o = tid >> 5, p = tid & 31;
        const int wsel = o >> 2, bsh = (o & 3) * 8;
        unsigned acc[8];
        #pragma unroll
        for (int n = 0; n < 8; ++n) acc[n] = 0u;   // +0,+0 f16; h>=0 exact
        #pragma unroll 4
        for (int l = 0; l < 64; ++l) {
            const unsigned hv = sh16[l * 32 + p];
            const unsigned mb = smask[l * 4 + wsel] >> bsh;
            #pragma unroll
            for (int n = 0; n < 8; ++n) {
                const int sel = (int)(mb << (31 - n)) >> 31;   // bit n -> 0/~0
                acc[n] = pk_max_f16(acc[n], hv & (unsigned)sel);
            }
        }
        // pagg[b][node][chunk][p], node = o*8+n
        unsigned* pp = pagg + ((size_t)(b * 128 + o * 8) * 8 + chunk) * 32 + p;
        #pragma unroll
        for (int n = 0; n < 8; ++n) pp[(size_t)n * 256] = acc[n];
    }
}

__global__ __launch_bounds__(512, 2) void k_fused2(
    const unsigned* __restrict__ pagg,
    const float* __restrict__ W3, const float* __restrict__ b3,
    const float* __restrict__ W4, const float* __restrict__ b4,
    const float* __restrict__ gamma, const float* __restrict__ beta,
    const float* __restrict__ W5, const float* __restrict__ b5,
    float* __restrict__ y, unsigned* __restrict__ counter,
    float* __restrict__ out)
{
    const int b   = blockIdx.x;     // 0..31
    const int tid = threadIdx.x;

    __shared__ float sagg[128 * 64];   // 32 KB
    __shared__ float sW3[1024];        // [64][16]
    __shared__ float sb3[16];
    __shared__ float sm[2048];         // [128][16]
    __shared__ float sred[8][64];
    __shared__ int   slast;
    __shared__ float sy[2048];
    __shared__ float sstat[3][64];

    sW3[tid]       = W3[tid];
    sW3[tid + 512] = W3[tid + 512];
    if (tid < 16) sb3[tid] = b3[tid];

    // ---- combine 8 chunk-partials: pair p = tid&31, nodes (tid>>5)*8..+7
    {
        const int p = tid & 31, ng = tid >> 5;
        #pragma unroll
        for (int n8 = 0; n8 < 8; ++n8) {
            const int node = ng * 8 + n8;
            const unsigned* pp = pagg + ((size_t)(b * 128 + node) * 8) * 32 + p;
            unsigned v = pp[0];
            #pragma unroll
            for (int ch = 1; ch < 8; ++ch) v = pk_max_f16(v, pp[ch * 32]);
            const __half2 hh = *(const __half2*)&v;
            *(float2*)&sagg[node * 64 + 2 * p] =
                make_float2(__low2float(hh), __high2float(hh));
        }
    }
    __syncthreads();

    // ---- f_macro: jj = tid&15, nodes (tid>>4)*4..+3 ----
    {
        const int jj = tid & 15, ng2 = tid >> 4;
        #pragma unroll
        for (int nn = 0; nn < 4; ++nn) {
            const int node = ng2 * 4 + nn;
            float a = sb3[jj];
            #pragma unroll
            for (int c = 0; c < 64; ++c) a += sagg[node * 64 + c] * sW3[c * 16 + jj];
            sm[node * 16 + jj] = fmaxf(a, 0.f);
        }
    }
    __syncthreads();

    // ---- W4 dot: o = tid&63, k-slice g = tid>>6 (256 k each) ----
    {
        const int o = tid & 63, g = tid >> 6;
        float a = 0.f;
        const float* wp = W4 + (size_t)(g * 256) * 64 + o;
        #pragma unroll 8
        for (int k = 0; k < 256; ++k) a += sm[g * 256 + k] * wp[(size_t)k * 64];
        sred[g][o] = a;
    }
    __syncthreads();
    if (tid < 64) {
        float v = b4[tid];
        #pragma unroll
        for (int g = 0; g < 8; ++g) v += sred[g][tid];
        y[b * 64 + tid] = fmaxf(v, 0.f);
    }
    __syncthreads();

    // ---- 32-block arrival; last block does BN + final linear ----
    if (tid == 0) {
        __threadfence();
        const unsigned old = atomicAdd(counter, 1u);
        slast = (old == 31u);
    }
    __syncthreads();
    if (!slast) return;
    __threadfence();

    #pragma unroll
    for (int idx = tid; idx < 2048; idx += 512)
        sy[idx] = __hip_atomic_load(&y[idx], __ATOMIC_RELAXED,
                                    __HIP_MEMORY_SCOPE_AGENT);
    __syncthreads();
    if (tid < 64) {
        float s1 = 0.f, s2 = 0.f;
        #pragma unroll
        for (int bb = 0; bb < 32; ++bb) {
            const float v = sy[bb * 64 + tid];
            s1 += v; s2 += v * v;
        }
        const float mean = s1 * (1.f / 32.f);
        const float var  = s2 * (1.f / 32.f) - mean * mean;  // biased, torch BN
        sstat[0][tid] = mean;
        sstat[1][tid] = gamma[tid] * rsqrtf(var + 1e-5f);
        sstat[2][tid] = beta[tid];
    }
    __syncthreads();
    if (tid < 320) {
        const int bb = tid / 10, q = tid % 10;
        float a = b5[q];
        #pragma unroll
        for (int o = 0; o < 64; ++o)
            a += ((sy[bb * 64 + o] - sstat[0][o]) * sstat[1][o] + sstat[2][o])
                 * W5[o * 10 + q];
        out[bb * 10 + q] = a;
    }
}

extern "C" void kernel_launch(void* const* d_in, const int* in_sizes, int n_in,
                              void* d_out, int out_size, void* d_ws, size_t ws_size,
                              hipStream_t stream) {
    const float* x     = (const float*)d_in[0];
    const float* tree  = (const float*)d_in[1];
    const float* W1    = (const float*)d_in[2];
    const float* b1    = (const float*)d_in[3];
    const float* W2    = (const float*)d_in[4];
    const float* b2    = (const float*)d_in[5];
    const float* W3    = (const float*)d_in[6];
    const float* b3    = (const float*)d_in[7];
    const float* W4    = (const float*)d_in[8];
    const float* b4    = (const float*)d_in[9];
    const float* gamma = (const float*)d_in[10];
    const float* beta  = (const float*)d_in[11];
    const float* W5    = (const float*)d_in[12];
    const float* b5    = (const float*)d_in[13];
    float* out = (float*)d_out;

    unsigned* pagg    = (unsigned*)d_ws;            // 32*128*8*32 u32 = 4 MB
    float*    y       = (float*)(pagg + 32 * 128 * 8 * 32);   // 2048 f32
    unsigned* counter = (unsigned*)(y + 2048);

    k_fused1<<<dim3(8, 32), 512, 0, stream>>>(x, tree, W1, b1, W2, b2,
                                              pagg, counter);
    k_fused2<<<32, 512, 0, stream>>>(pagg, W3, b3, W4, b4, gamma, beta,
                                     W5, b5, y, counter, out);
}

// Round 11
// 36.992 us; speedup vs baseline: 1.0053x; 1.0053x over previous
//
#include <hip/hip_runtime.h>
#include <hip/hip_fp16.h>

// B=32, L=512, N=128, IN=16, OUT=10
// Two kernels, one boundary:
//  K1 k_micro: h16 = (half2)relu(relu(x@W1+b1)@W2+b2); block 0 zeroes
//              yfix[2048] (Q32.32) + arrival counter (poison-safe).
//  K2 k_agg_part (512 blocks): f16 bitmask max-agg + f_macro + W4 slice;
//              slice -> Q32.32 fixed point -> integer atomicAdd into yfix
//              (exactly associative => deterministic). Fence + 512-arrival;
//              last block: 2048 agent loads of yfix -> +b4,ReLU -> BN -> @W5+b5.

static __device__ __forceinline__ unsigned pk_max_f16(unsigned a, unsigned b) {
    unsigned r;
    asm("v_pk_max_f16 %0, %1, %2" : "=v"(r) : "v"(a), "v"(b));
    return r;
}

__global__ __launch_bounds__(256) void k_micro(
    const float* __restrict__ x, const float* __restrict__ W1,
    const float* __restrict__ b1, const float* __restrict__ W2,
    const float* __restrict__ b2, unsigned* __restrict__ h16,
    unsigned long long* __restrict__ yfix, unsigned* __restrict__ counter)
{
    const int tid = threadIdx.x;
    const int r = tid >> 5;                 // row within block (0..7)
    const int p = tid & 31;                 // channel pair (ch 2p, 2p+1)
    const int row0 = blockIdx.x * 8;

    if (blockIdx.x == 0) {                  // reset accumulators each call
        for (int i = tid; i < 2048; i += 256) yfix[i] = 0ull;
        if (tid == 0) *counter = 0u;
    }

    __shared__ float sx[8][16];
    __shared__ float sh1[8][32];

    if (tid < 128) sx[tid >> 4][tid & 15] = x[(size_t)row0 * 16 + tid];

    float2 w2[32];
    #pragma unroll
    for (int j = 0; j < 32; ++j) w2[j] = *(const float2*)&W2[j * 64 + 2 * p];
    const float2 b2p = *(const float2*)&b2[2 * p];
    __syncthreads();

    {   // layer1: 256 thr = 8 rows x 32 cols
        const int rr = tid >> 5, c = tid & 31;
        float a = b1[c];
        #pragma unroll
        for (int i = 0; i < 16; ++i) a += sx[rr][i] * W1[i * 32 + c];
        sh1[rr][c] = fmaxf(a, 0.f);
    }
    __syncthreads();

    {   // layer2: 2 channels/thread, pack f16x2
        float a0 = b2p.x, a1 = b2p.y;
        #pragma unroll
        for (int j = 0; j < 32; ++j) {
            float v = sh1[r][j];
            a0 += v * w2[j].x;
            a1 += v * w2[j].y;
        }
        __half2 hp = __floats2half2_rn(fmaxf(a0, 0.f), fmaxf(a1, 0.f));
        h16[(size_t)(row0 + r) * 32 + p] = *(unsigned*)&hp;
    }
}

// grid 512 (XCD-swizzled), 512 threads = 8 waves.
__global__ __launch_bounds__(512, 4) void k_agg_part(
    const unsigned* __restrict__ h16,  // [B][512][32] f16x2
    const float* __restrict__ tree,    // [128][512]
    const float* __restrict__ W3, const float* __restrict__ b3,
    const float* __restrict__ W4, const float* __restrict__ b4,
    const float* __restrict__ gamma, const float* __restrict__ beta,
    const float* __restrict__ W5, const float* __restrict__ b5,
    unsigned long long* __restrict__ yfix, unsigned* __restrict__ counter,
    float* __restrict__ out)
{
    const int id   = blockIdx.x;          // 0..511
    const int b    = (id & 7) * 4 + ((id >> 3) & 3);
    const int ng   = id >> 5;             // 0..15 (nodes ng*8 .. ng*8+7)
    const int tid  = threadIdx.x;
    const int w    = tid >> 6;            // wave 0..7
    const int lane = tid & 63;
    const int half = lane >> 5;           // which of 2 leaves per iter
    const int p    = lane & 31;           // channel pair

    __shared__ unsigned smask[512];
    __shared__ float sred[8][8][64];
    __shared__ float sagg[8][64];
    __shared__ float sm[128];
    __shared__ float spart[8][64];
    __shared__ int   slast;
    __shared__ float sy[2048];
    __shared__ float sstat[3][64];

    // ---- per-leaf masks ----
    {
        unsigned bits = 0;
        const float* tp = tree + (size_t)(ng * 8) * 512 + tid;
        #pragma unroll
        for (int n = 0; n < 8; ++n)
            if (tp[(size_t)n * 512] > 0.5f) bits |= (1u << n);
        smask[tid] = bits;
    }
    __syncthreads();

    // ---- packed max-aggregation: wave w owns leaves w*64..w*64+63 ----
    unsigned acc[8];
    #pragma unroll
    for (int n = 0; n < 8; ++n) acc[n] = 0u;        // +0,+0 f16; h>=0 exact

    const unsigned* hb = h16 + (size_t)b * 16384 + (size_t)(w * 64 + half) * 32 + p;
    const unsigned* mp = &smask[w * 64 + half];
    #pragma unroll 8
    for (int j = 0; j < 32; ++j) {
        unsigned hv  = hb[(size_t)(2 * j) * 32];
        unsigned msk = mp[2 * j];
        #pragma unroll
        for (int n = 0; n < 8; ++n) {
            int sel = (int)(msk << (31 - n)) >> 31;
            acc[n] = pk_max_f16(acc[n], hv & (unsigned)sel);
        }
    }
    #pragma unroll
    for (int n = 0; n < 8; ++n) {
        int bi = __shfl_xor((int)acc[n], 32);
        acc[n] = pk_max_f16(acc[n], (unsigned)bi);
    }
    if (half == 0) {
        #pragma unroll
        for (int n = 0; n < 8; ++n) {
            __half2 hh = *(__half2*)&acc[n];
            float2 v = make_float2(__low2float(hh), __high2float(hh));
            *(float2*)&sred[w][n][2 * p] = v;
        }
    }
    __syncthreads();

    {   // combine 8 waves
        const int n = tid >> 6, c = tid & 63;
        float v = sred[0][n][c];
        #pragma unroll
        for (int ww = 1; ww < 8; ++ww) v = fmaxf(v, sred[ww][n][c]);
        sagg[n][c] = v;
    }
    __syncthreads();

    // ---- f_macro ----
    if (tid < 128) {
        int n = tid >> 4, jj = tid & 15;
        float a = b3[jj];
        #pragma unroll
        for (int c2 = 0; c2 < 64; ++c2)
            a += sagg[n][c2] * W3[c2 * 16 + jj];
        sm[tid] = fmaxf(a, 0.f);
    }
    __syncthreads();

    // ---- W4 slice ----
    {
        float a = 0.f;
        const float* w4p = W4 + (size_t)(ng * 128 + w * 16) * 64 + lane;
        #pragma unroll
        for (int k2 = 0; k2 < 16; ++k2)
            a += sm[w * 16 + k2] * w4p[(size_t)k2 * 64];
        spart[w][lane] = a;
    }
    __syncthreads();
    if (tid < 64) {
        float v = 0.f;
        #pragma unroll
        for (int ww = 0; ww < 8; ++ww) v += spart[ww][tid];
        // Q32.32 fixed point: integer add is associative -> deterministic
        long long q = llrintf(v * 4294967296.0f);
        atomicAdd(&yfix[(size_t)b * 64 + tid], (unsigned long long)q);
    }
    __syncthreads();

    // ---- arrival; last block: BN + final linear ----
    if (tid == 0) {
        __threadfence();
        unsigned old = atomicAdd(counter, 1u);
        slast = (old == 511u);
    }
    __syncthreads();
    if (!slast) return;
    __threadfence();

    #pragma unroll
    for (int idx = tid; idx < 2048; idx += 512) {
        long long v = (long long)__hip_atomic_load(&yfix[idx], __ATOMIC_RELAXED,
                                                   __HIP_MEMORY_SCOPE_AGENT);
        float fv = (float)v * (1.0f / 4294967296.0f);
        sy[idx] = fmaxf(fv + b4[idx & 63], 0.f);
    }
    __syncthreads();
    if (tid < 64) {
        float s1 = 0.f, s2 = 0.f;
        #pragma unroll
        for (int bb = 0; bb < 32; ++bb) {
            const float v = sy[bb * 64 + tid];
            s1 += v; s2 += v * v;
        }
        const float mean = s1 * (1.f / 32.f);
        const float var  = s2 * (1.f / 32.f) - mean * mean;  // biased, torch BN
        sstat[0][tid] = mean;
        sstat[1][tid] = gamma[tid] * rsqrtf(var + 1e-5f);
        sstat[2][tid] = beta[tid];
    }
    __syncthreads();
    if (tid < 320) {
        const int bb = tid / 10, q = tid % 10;
        float a = b5[q];
        #pragma unroll
        for (int o = 0; o < 64; ++o)
            a += ((sy[bb * 64 + o] - sstat[0][o]) * sstat[1][o] + sstat[2][o])
                 * W5[o * 10 + q];
        out[bb * 10 + q] = a;
    }
}

extern "C" void kernel_launch(void* const* d_in, const int* in_sizes, int n_in,
                              void* d_out, int out_size, void* d_ws, size_t ws_size,
                              hipStream_t stream) {
    const float* x     = (const float*)d_in[0];
    const float* tree  = (const float*)d_in[1];
    const float* W1    = (const float*)d_in[2];
    const float* b1    = (const float*)d_in[3];
    const float* W2    = (const float*)d_in[4];
    const float* b2    = (const float*)d_in[5];
    const float* W3    = (const float*)d_in[6];
    const float* b3    = (const float*)d_in[7];
    const float* W4    = (const float*)d_in[8];
    const float* b4    = (const float*)d_in[9];
    const float* gamma = (const float*)d_in[10];
    const float* beta  = (const float*)d_in[11];
    const float* W5    = (const float*)d_in[12];
    const float* b5    = (const float*)d_in[13];
    float* out = (float*)d_out;

    unsigned*           h16     = (unsigned*)d_ws;                 // 2 MB
    unsigned long long* yfix    = (unsigned long long*)(h16 + 16384 * 32); // 16 KB
    unsigned*           counter = (unsigned*)(yfix + 2048);

    k_micro   <<<2048, 256, 0, stream>>>(x, W1, b1, W2, b2, h16, yfix, counter);
    k_agg_part<<<512,  512, 0, stream>>>(h16, tree, W3, b3, W4, b4,
                                         gamma, beta, W5, b5,
                                         yfix, counter, out);
}

// Round 12
// 30.117 us; speedup vs baseline: 1.2347x; 1.2283x over previous
//
#include <hip/hip_runtime.h>
#include <hip/hip_fp16.h>

// B=32, L=512, N=128, IN=16, OUT=10
// Three kernels (R9 fence-free skeleton), Q32.32 y-accumulation:
//  K1 k_micro   : h16 = (half2)relu(relu(x@W1+b1)@W2+b2); block 0 zeroes yfix.
//  K2 k_agg_part: f16 bitmask max-agg (dwordx2 loads) + f_macro + W4 slice;
//                 slice -> Q32.32 -> integer atomicAdd into yfix[2048]
//                 (associative => deterministic). No fences, no arrival.
//  K3 k_bn_out  : yfix -> y=relu(.+b4); BatchNorm (batch stats); @W5+b5.

static __device__ __forceinline__ unsigned pk_max_f16(unsigned a, unsigned b) {
    unsigned r;
    asm("v_pk_max_f16 %0, %1, %2" : "=v"(r) : "v"(a), "v"(b));
    return r;
}

__global__ __launch_bounds__(256) void k_micro(
    const float* __restrict__ x, const float* __restrict__ W1,
    const float* __restrict__ b1, const float* __restrict__ W2,
    const float* __restrict__ b2, unsigned* __restrict__ h16,
    unsigned long long* __restrict__ yfix)
{
    const int tid = threadIdx.x;
    const int r = tid >> 5;                 // row within block (0..7)
    const int p = tid & 31;                 // channel pair (ch 2p, 2p+1)
    const int row0 = blockIdx.x * 8;

    if (blockIdx.x == 0) {                  // reset Q32.32 accumulators
        for (int i = tid; i < 2048; i += 256) yfix[i] = 0ull;
    }

    __shared__ float sx[8][16];
    __shared__ float sh1[8][32];

    if (tid < 128) sx[tid >> 4][tid & 15] = x[(size_t)row0 * 16 + tid];

    float2 w2[32];
    #pragma unroll
    for (int j = 0; j < 32; ++j) w2[j] = *(const float2*)&W2[j * 64 + 2 * p];
    const float2 b2p = *(const float2*)&b2[2 * p];
    __syncthreads();

    {   // layer1: 256 thr = 8 rows x 32 cols
        const int rr = tid >> 5, c = tid & 31;
        float a = b1[c];
        #pragma unroll
        for (int i = 0; i < 16; ++i) a += sx[rr][i] * W1[i * 32 + c];
        sh1[rr][c] = fmaxf(a, 0.f);
    }
    __syncthreads();

    {   // layer2: 2 channels/thread, pack f16x2
        float a0 = b2p.x, a1 = b2p.y;
        #pragma unroll
        for (int j = 0; j < 32; ++j) {
            float v = sh1[r][j];
            a0 += v * w2[j].x;
            a1 += v * w2[j].y;
        }
        __half2 hp = __floats2half2_rn(fmaxf(a0, 0.f), fmaxf(a1, 0.f));
        h16[(size_t)(row0 + r) * 32 + p] = *(unsigned*)&hp;
    }
}

// grid 512 (XCD-swizzled), 512 threads = 8 waves.
__global__ __launch_bounds__(512, 4) void k_agg_part(
    const unsigned* __restrict__ h16,  // [B][512][32] f16x2
    const float* __restrict__ tree,    // [128][512]
    const float* __restrict__ W3, const float* __restrict__ b3,
    const float* __restrict__ W4,
    unsigned long long* __restrict__ yfix)
{
    const int id   = blockIdx.x;          // 0..511
    const int b    = (id & 7) * 4 + ((id >> 3) & 3);
    const int ng   = id >> 5;             // 0..15 (nodes ng*8 .. ng*8+7)
    const int tid  = threadIdx.x;
    const int w    = tid >> 6;            // wave 0..7
    const int lane = tid & 63;
    const int g2   = lane >> 4;           // leaf-group 0..3
    const int p2   = lane & 15;           // pair-pair (channels 4*p2..4*p2+3)

    __shared__ unsigned smask[512];
    __shared__ float sred[8][8][64];
    __shared__ float sagg[8][64];
    __shared__ float sm[128];
    __shared__ float spart[8][64];

    // ---- per-leaf masks (thread owns leaf tid; coalesced) ----
    {
        unsigned bits = 0;
        const float* tp = tree + (size_t)(ng * 8) * 512 + tid;
        #pragma unroll
        for (int n = 0; n < 8; ++n)
            if (tp[(size_t)n * 512] > 0.5f) bits |= (1u << n);
        smask[tid] = bits;
    }
    __syncthreads();

    // ---- packed max-agg, dwordx2 loads: wave w owns leaves w*64..+63 ----
    // lane handles leaf w*64 + 4j + g2, channels 4*p2..4*p2+3.
    unsigned accL[8], accH[8];
    #pragma unroll
    for (int n = 0; n < 8; ++n) { accL[n] = 0u; accH[n] = 0u; }  // h>=0 exact

    const uint2* hb = (const uint2*)(h16 + (size_t)b * 16384
                                     + (size_t)(w * 64 + g2) * 32 + 2 * p2);
    const unsigned* mp = &smask[w * 64 + g2];
    #pragma unroll 8
    for (int j = 0; j < 16; ++j) {
        const uint2 hv = hb[(size_t)j * 64];     // 2 u32 = 4 f16 ch (8B load)
        const unsigned mb = mp[4 * j];           // LDS b32 broadcast
        #pragma unroll
        for (int n = 0; n < 8; ++n) {
            const int sel = (int)(mb << (31 - n)) >> 31;   // bit n -> 0 / ~0
            accL[n] = pk_max_f16(accL[n], hv.x & (unsigned)sel);
            accH[n] = pk_max_f16(accH[n], hv.y & (unsigned)sel);
        }
    }
    // combine the 4 leaf-groups (lanes differing in bits 4,5)
    #pragma unroll
    for (int n = 0; n < 8; ++n) {
        accL[n] = pk_max_f16(accL[n], (unsigned)__shfl_xor((int)accL[n], 16));
        accH[n] = pk_max_f16(accH[n], (unsigned)__shfl_xor((int)accH[n], 16));
        accL[n] = pk_max_f16(accL[n], (unsigned)__shfl_xor((int)accL[n], 32));
        accH[n] = pk_max_f16(accH[n], (unsigned)__shfl_xor((int)accH[n], 32));
    }
    if (g2 == 0) {
        #pragma unroll
        for (int n = 0; n < 8; ++n) {
            const __half2 lo = *(const __half2*)&accL[n];
            const __half2 hi = *(const __half2*)&accH[n];
            *(float2*)&sred[w][n][4 * p2] =
                make_float2(__low2float(lo), __high2float(lo));
            *(float2*)&sred[w][n][4 * p2 + 2] =
                make_float2(__low2float(hi), __high2float(hi));
        }
    }
    __syncthreads();

    {   // combine 8 waves: tid covers (n=tid>>6, c=tid&63)
        const int n = tid >> 6, c = tid & 63;
        float v = sred[0][n][c];
        #pragma unroll
        for (int ww = 1; ww < 8; ++ww) v = fmaxf(v, sred[ww][n][c]);
        sagg[n][c] = v;
    }
    __syncthreads();

    // ---- f_macro ----
    if (tid < 128) {
        const int n = tid >> 4, jj = tid & 15;
        float a = b3[jj];
        #pragma unroll
        for (int c2 = 0; c2 < 64; ++c2)
            a += sagg[n][c2] * W3[c2 * 16 + jj];
        sm[tid] = fmaxf(a, 0.f);
    }
    __syncthreads();

    // ---- W4 slice ----
    {
        float a = 0.f;
        const float* w4p = W4 + (size_t)(ng * 128 + w * 16) * 64 + lane;
        #pragma unroll
        for (int k2 = 0; k2 < 16; ++k2)
            a += sm[w * 16 + k2] * w4p[(size_t)k2 * 64];
        spart[w][lane] = a;
    }
    __syncthreads();
    if (tid < 64) {
        float v = 0.f;
        #pragma unroll
        for (int ww = 0; ww < 8; ++ww) v += spart[ww][tid];
        // Q32.32: integer add is associative -> deterministic
        const long long q = llrintf(v * 4294967296.0f);
        atomicAdd(&yfix[(size_t)b * 64 + tid], (unsigned long long)q);
    }
}

// yfix -> y = relu(.+b4); BatchNorm (batch stats over B=32); @W5+b5.
__global__ __launch_bounds__(1024) void k_bn_out(
    const unsigned long long* __restrict__ yfix, const float* __restrict__ b4,
    const float* __restrict__ gamma, const float* __restrict__ beta,
    const float* __restrict__ W5, const float* __restrict__ b5,
    float* __restrict__ out)
{
    const int tid = threadIdx.x;
    __shared__ float sy[32 * 64];
    __shared__ float smean[64], sscale[64], sbeta[64];

    #pragma unroll
    for (int idx = tid; idx < 2048; idx += 1024) {
        const long long v = (long long)yfix[idx];
        sy[idx] = fmaxf((float)v * (1.0f / 4294967296.0f) + b4[idx & 63], 0.f);
    }
    __syncthreads();
    if (tid < 64) {
        float s1 = 0.f, s2 = 0.f;
        #pragma unroll
        for (int b = 0; b < 32; ++b) {
            const float v = sy[b * 64 + tid];
            s1 += v; s2 += v * v;
        }
        const float mean = s1 * (1.f / 32.f);
        const float var  = s2 * (1.f / 32.f) - mean * mean;  // biased, torch BN
        smean[tid]  = mean;
        sscale[tid] = gamma[tid] * rsqrtf(var + 1e-5f);
        sbeta[tid]  = beta[tid];
    }
    __syncthreads();
    if (tid < 320) {
        const int b = tid / 10, q = tid % 10;
        float acc = b5[q];
        #pragma unroll
        for (int o = 0; o < 64; ++o)
            acc += ((sy[b * 64 + o] - smean[o]) * sscale[o] + sbeta[o])
                   * W5[o * 10 + q];
        out[b * 10 + q] = acc;
    }
}

extern "C" void kernel_launch(void* const* d_in, const int* in_sizes, int n_in,
                              void* d_out, int out_size, void* d_ws, size_t ws_size,
                              hipStream_t stream) {
    const float* x     = (const float*)d_in[0];
    const float* tree  = (const float*)d_in[1];
    const float* W1    = (const float*)d_in[2];
    const float* b1    = (const float*)d_in[3];
    const float* W2    = (const float*)d_in[4];
    const float* b2    = (const float*)d_in[5];
    const float* W3    = (const float*)d_in[6];
    const float* b3    = (const float*)d_in[7];
    const float* W4    = (const float*)d_in[8];
    const float* b4    = (const float*)d_in[9];
    const float* gamma = (const float*)d_in[10];
    const float* beta  = (const float*)d_in[11];
    const float* W5    = (const float*)d_in[12];
    const float* b5    = (const float*)d_in[13];
    float* out = (float*)d_out;

    unsigned*           h16  = (unsigned*)d_ws;                       // 2 MB
    unsigned long long* yfix = (unsigned long long*)(h16 + 16384 * 32); // 16 KB

    k_micro   <<<2048, 256, 0, stream>>>(x, W1, b1, W2, b2, h16, yfix);
    k_agg_part<<<512,  512, 0, stream>>>(h16, tree, W3, b3, W4, yfix);
    k_bn_out  <<<1,   1024, 0, stream>>>(yfix, b4, gamma, beta, W5, b5, out);
}

// Round 13
// 28.550 us; speedup vs baseline: 1.3025x; 1.0549x over previous
//
#include <hip/hip_runtime.h>
#include <hip/hip_fp16.h>

// B=32, L=512, N=128, IN=16, OUT=10
// Three kernels (R9/R12 fence-free skeleton) + XCD affinity:
//  K1 k_micro   : h16 = (half2)relu(relu(x@W1+b1)@W2+b2); blocks of batch b
//                 pinned to XCD b%8 (blockIdx%8 heuristic) so h16[b] lands in
//                 one XCD's L2. Block 0 zeroes yfix.
//  K2 k_agg_part: same-XCD readers: f16 bitmask max-agg + f_macro + W4 slice;
//                 Q32.32 integer atomicAdd into yfix[2048] (associative).
//  K3 k_bn_out  : yfix -> y=relu(.+b4); BatchNorm (batch stats); @W5+b5.

static __device__ __forceinline__ unsigned pk_max_f16(unsigned a, unsigned b) {
    unsigned r;
    asm("v_pk_max_f16 %0, %1, %2" : "=v"(r) : "v"(a), "v"(b));
    return r;
}

__global__ __launch_bounds__(256) void k_micro(
    const float* __restrict__ x, const float* __restrict__ W1,
    const float* __restrict__ b1, const float* __restrict__ W2,
    const float* __restrict__ b2, unsigned* __restrict__ h16,
    unsigned long long* __restrict__ yfix)
{
    const int gid = blockIdx.x;             // 0..2047
    const int xcd = gid & 7;
    const int rb  = (gid >> 3) & 63;        // row-block within batch (0..63)
    const int bq  = gid >> 9;               // 0..3
    const int b   = bq * 8 + xcd;           // batch pinned to XCD b%8
    const int row0 = b * 512 + rb * 8;

    const int tid = threadIdx.x;
    const int r = tid >> 5;                 // row within block (0..7)
    const int p = tid & 31;                 // channel pair (ch 2p, 2p+1)

    if (gid == 0) {                         // reset Q32.32 accumulators
        for (int i = tid; i < 2048; i += 256) yfix[i] = 0ull;
    }

    __shared__ float sx[8][16];
    __shared__ float sh1[8][32];

    if (tid < 128) sx[tid >> 4][tid & 15] = x[(size_t)row0 * 16 + tid];

    float2 w2[32];
    #pragma unroll
    for (int j = 0; j < 32; ++j) w2[j] = *(const float2*)&W2[j * 64 + 2 * p];
    const float2 b2p = *(const float2*)&b2[2 * p];
    __syncthreads();

    {   // layer1: 256 thr = 8 rows x 32 cols
        const int rr = tid >> 5, c = tid & 31;
        float a = b1[c];
        #pragma unroll
        for (int i = 0; i < 16; ++i) a += sx[rr][i] * W1[i * 32 + c];
        sh1[rr][c] = fmaxf(a, 0.f);
    }
    __syncthreads();

    {   // layer2: 2 channels/thread, pack f16x2
        float a0 = b2p.x, a1 = b2p.y;
        #pragma unroll
        for (int j = 0; j < 32; ++j) {
            float v = sh1[r][j];
            a0 += v * w2[j].x;
            a1 += v * w2[j].y;
        }
        __half2 hp = __floats2half2_rn(fmaxf(a0, 0.f), fmaxf(a1, 0.f));
        h16[(size_t)(row0 + r) * 32 + p] = *(unsigned*)&hp;
    }
}

// grid 512, 512 threads = 8 waves. Readers of batch b pinned to XCD b%8.
__global__ __launch_bounds__(512, 4) void k_agg_part(
    const unsigned* __restrict__ h16,  // [B][512][32] f16x2
    const float* __restrict__ tree,    // [128][512]
    const float* __restrict__ W3, const float* __restrict__ b3,
    const float* __restrict__ W4,
    unsigned long long* __restrict__ yfix)
{
    const int id   = blockIdx.x;          // 0..511
    const int xcd  = id & 7;
    const int ng   = (id >> 3) & 15;      // nodes ng*8 .. ng*8+7
    const int bq   = id >> 7;             // 0..3
    const int b    = bq * 8 + xcd;        // same XCD as K1's writers of b
    const int tid  = threadIdx.x;
    const int w    = tid >> 6;            // wave 0..7
    const int lane = tid & 63;
    const int g2   = lane >> 4;           // leaf-group 0..3
    const int p2   = lane & 15;           // pair-pair (channels 4*p2..4*p2+3)

    __shared__ unsigned smask[512];
    __shared__ float sred[8][8][64];
    __shared__ float sagg[8][64];
    __shared__ float sm[128];
    __shared__ float spart[8][64];

    // ---- per-leaf masks (thread owns leaf tid; coalesced) ----
    {
        unsigned bits = 0;
        const float* tp = tree + (size_t)(ng * 8) * 512 + tid;
        #pragma unroll
        for (int n = 0; n < 8; ++n)
            if (tp[(size_t)n * 512] > 0.5f) bits |= (1u << n);
        smask[tid] = bits;
    }
    __syncthreads();

    // ---- packed max-agg, dwordx2 loads: wave w owns leaves w*64..+63 ----
    unsigned accL[8], accH[8];
    #pragma unroll
    for (int n = 0; n < 8; ++n) { accL[n] = 0u; accH[n] = 0u; }  // h>=0 exact

    const uint2* hb = (const uint2*)(h16 + (size_t)b * 16384
                                     + (size_t)(w * 64 + g2) * 32 + 2 * p2);
    const unsigned* mp = &smask[w * 64 + g2];
    #pragma unroll 16
    for (int j = 0; j < 16; ++j) {
        const uint2 hv = hb[(size_t)j * 64];     // 4 f16 ch (8B, local L2)
        const unsigned mb = mp[4 * j];           // LDS b32 broadcast
        #pragma unroll
        for (int n = 0; n < 8; ++n) {
            const int sel = (int)(mb << (31 - n)) >> 31;   // bit n -> 0 / ~0
            accL[n] = pk_max_f16(accL[n], hv.x & (unsigned)sel);
            accH[n] = pk_max_f16(accH[n], hv.y & (unsigned)sel);
        }
    }
    // combine the 4 leaf-groups (lanes differing in bits 4,5)
    #pragma unroll
    for (int n = 0; n < 8; ++n) {
        accL[n] = pk_max_f16(accL[n], (unsigned)__shfl_xor((int)accL[n], 16));
        accH[n] = pk_max_f16(accH[n], (unsigned)__shfl_xor((int)accH[n], 16));
        accL[n] = pk_max_f16(accL[n], (unsigned)__shfl_xor((int)accL[n], 32));
        accH[n] = pk_max_f16(accH[n], (unsigned)__shfl_xor((int)accH[n], 32));
    }
    if (g2 == 0) {
        #pragma unroll
        for (int n = 0; n < 8; ++n) {
            const __half2 lo = *(const __half2*)&accL[n];
            const __half2 hi = *(const __half2*)&accH[n];
            *(float2*)&sred[w][n][4 * p2] =
                make_float2(__low2float(lo), __high2float(lo));
            *(float2*)&sred[w][n][4 * p2 + 2] =
                make_float2(__low2float(hi), __high2float(hi));
        }
    }
    __syncthreads();

    {   // combine 8 waves: tid covers (n=tid>>6, c=tid&63)
        const int n = tid >> 6, c = tid & 63;
        float v = sred[0][n][c];
        #pragma unroll
        for (int ww = 1; ww < 8; ++ww) v = fmaxf(v, sred[ww][n][c]);
        sagg[n][c] = v;
    }
    __syncthreads();

    // ---- f_macro ----
    if (tid < 128) {
        const int n = tid >> 4, jj = tid & 15;
        float a = b3[jj];
        #pragma unroll
        for (int c2 = 0; c2 < 64; ++c2)
            a += sagg[n][c2] * W3[c2 * 16 + jj];
        sm[tid] = fmaxf(a, 0.f);
    }
    __syncthreads();

    // ---- W4 slice ----
    {
        float a = 0.f;
        const float* w4p = W4 + (size_t)(ng * 128 + w * 16) * 64 + lane;
        #pragma unroll
        for (int k2 = 0; k2 < 16; ++k2)
            a += sm[w * 16 + k2] * w4p[(size_t)k2 * 64];
        spart[w][lane] = a;
    }
    __syncthreads();
    if (tid < 64) {
        float v = 0.f;
        #pragma unroll
        for (int ww = 0; ww < 8; ++ww) v += spart[ww][tid];
        // Q32.32: integer add is associative -> deterministic
        const long long q = llrintf(v * 4294967296.0f);
        atomicAdd(&yfix[(size_t)b * 64 + tid], (unsigned long long)q);
    }
}

// yfix -> y = relu(.+b4); BatchNorm (batch stats over B=32); @W5+b5.
__global__ __launch_bounds__(1024) void k_bn_out(
    const unsigned long long* __restrict__ yfix, const float* __restrict__ b4,
    const float* __restrict__ gamma, const float* __restrict__ beta,
    const float* __restrict__ W5, const float* __restrict__ b5,
    float* __restrict__ out)
{
    const int tid = threadIdx.x;
    __shared__ float sy[32 * 64];
    __shared__ float smean[64], sscale[64], sbeta[64];

    #pragma unroll
    for (int idx = tid; idx < 2048; idx += 1024) {
        const long long v = (long long)yfix[idx];
        sy[idx] = fmaxf((float)v * (1.0f / 4294967296.0f) + b4[idx & 63], 0.f);
    }
    __syncthreads();
    if (tid < 64) {
        float s1 = 0.f, s2 = 0.f;
        #pragma unroll
        for (int b = 0; b < 32; ++b) {
            const float v = sy[b * 64 + tid];
            s1 += v; s2 += v * v;
        }
        const float mean = s1 * (1.f / 32.f);
        const float var  = s2 * (1.f / 32.f) - mean * mean;  // biased, torch BN
        smean[tid]  = mean;
        sscale[tid] = gamma[tid] * rsqrtf(var + 1e-5f);
        sbeta[tid]  = beta[tid];
    }
    __syncthreads();
    if (tid < 320) {
        const int b = tid / 10, q = tid % 10;
        float acc = b5[q];
        #pragma unroll
        for (int o = 0; o < 64; ++o)
            acc += ((sy[b * 64 + o] - smean[o]) * sscale[o] + sbeta[o])
                   * W5[o * 10 + q];
        out[b * 10 + q] = acc;
    }
}

extern "C" void kernel_launch(void* const* d_in, const int* in_sizes, int n_in,
                              void* d_out, int out_size, void* d_ws, size_t ws_size,
                              hipStream_t stream) {
    const float* x     = (const float*)d_in[0];
    const float* tree  = (const float*)d_in[1];
    const float* W1    = (const float*)d_in[2];
    const float* b1    = (const float*)d_in[3];
    const float* W2    = (const float*)d_in[4];
    const float* b2    = (const float*)d_in[5];
    const float* W3    = (const float*)d_in[6];
    const float* b3    = (const float*)d_in[7];
    const float* W4    = (const float*)d_in[8];
    const float* b4    = (const float*)d_in[9];
    const float* gamma = (const float*)d_in[10];
    const float* beta  = (const float*)d_in[11];
    const float* W5    = (const float*)d_in[12];
    const float* b5    = (const float*)d_in[13];
    float* out = (float*)d_out;

    unsigned*           h16  = (unsigned*)d_ws;                       // 2 MB
    unsigned long long* yfix = (unsigned long long*)(h16 + 16384 * 32); // 16 KB

    k_micro   <<<2048, 256, 0, stream>>>(x, W1, b1, W2, b2, h16, yfix);
    k_agg_part<<<512,  512, 0, stream>>>(h16, tree, W3, b3, W4, yfix);
    k_bn_out  <<<1,   1024, 0, stream>>>(yfix, b4, gamma, beta, W5, b5, out);
}

// Round 14
// 22.990 us; speedup vs baseline: 1.6176x; 1.2419x over previous
//
#include <hip/hip_runtime.h>
#include <hip/hip_fp16.h>

// B=32, L=512, N=128, IN=16, OUT=10
// Three kernels (R13 skeleton + XCD affinity), K1 reuses weights 4x:
//  K1 k_micro   : 512 blocks x 32 rows; W1/W2 columns in registers, reused
//                 across 4 row-passes (L2 W2 traffic 134->33 MB). Blocks of
//                 batch b pinned to XCD b%8. Block 0 zeroes yfix.
//  K2 k_agg_part: same-XCD readers; f16 bitmask max-agg + f_macro + W4 slice;
//                 Q32.32 integer atomicAdd into yfix[2048] (associative).
//  K3 k_bn_out  : yfix -> y=relu(.+b4); BatchNorm (batch stats); @W5+b5.

static __device__ __forceinline__ unsigned pk_max_f16(unsigned a, unsigned b) {
    unsigned r;
    asm("v_pk_max_f16 %0, %1, %2" : "=v"(r) : "v"(a), "v"(b));
    return r;
}

__global__ __launch_bounds__(256) void k_micro(
    const float* __restrict__ x, const float* __restrict__ W1,
    const float* __restrict__ b1, const float* __restrict__ W2,
    const float* __restrict__ b2, unsigned* __restrict__ h16,
    unsigned long long* __restrict__ yfix)
{
    const int gid = blockIdx.x;             // 0..511
    const int xcd = gid & 7;
    const int t   = gid >> 3;               // 0..63
    const int bq  = t >> 4;                 // 0..3
    const int rb  = t & 15;                 // 0..15
    const int b   = bq * 8 + xcd;           // batch pinned to XCD b%8
    const int row0 = b * 512 + rb * 32;     // 32 rows per block

    const int tid = threadIdx.x;
    const int r = tid >> 5;                 // row-in-pass (0..7)
    const int p = tid & 31;                 // channel pair / layer1 col

    if (gid == 0) {                         // reset Q32.32 accumulators
        for (int i = tid; i < 2048; i += 256) yfix[i] = 0ull;
    }

    __shared__ float sx[32][16];            // 2 KB
    __shared__ float sh1[32][32];           // 4 KB

    // stage x for 32 rows (512 floats, 2 per thread)
    {
        float v0 = x[(size_t)row0 * 16 + tid];
        float v1 = x[(size_t)row0 * 16 + 256 + tid];
        ((float*)sx)[tid]       = v0;
        ((float*)sx)[tid + 256] = v1;
    }

    // weight columns in registers, reused across 4 passes
    float w1c[16];
    #pragma unroll
    for (int i = 0; i < 16; ++i) w1c[i] = W1[i * 32 + p];
    float2 w2[32];
    #pragma unroll
    for (int j = 0; j < 32; ++j) w2[j] = *(const float2*)&W2[j * 64 + 2 * p];
    const float  b1c = b1[p];
    const float2 b2p = *(const float2*)&b2[2 * p];
    __syncthreads();

    // layer1: 4 passes x (8 rows x 32 cols)
    #pragma unroll
    for (int q = 0; q < 4; ++q) {
        const int row = q * 8 + r;
        float a = b1c;
        #pragma unroll
        for (int i = 0; i < 16; ++i) a += sx[row][i] * w1c[i];
        sh1[row][p] = fmaxf(a, 0.f);
    }
    __syncthreads();

    // layer2: 4 passes, 2 channels/thread, pack f16x2
    #pragma unroll
    for (int q = 0; q < 4; ++q) {
        const int row = q * 8 + r;
        float a0 = b2p.x, a1 = b2p.y;
        #pragma unroll
        for (int j = 0; j < 32; ++j) {
            const float v = sh1[row][j];
            a0 += v * w2[j].x;
            a1 += v * w2[j].y;
        }
        __half2 hp = __floats2half2_rn(fmaxf(a0, 0.f), fmaxf(a1, 0.f));
        h16[(size_t)(row0 + row) * 32 + p] = *(unsigned*)&hp;
    }
}

// grid 512, 512 threads = 8 waves. Readers of batch b pinned to XCD b%8.
__global__ __launch_bounds__(512, 4) void k_agg_part(
    const unsigned* __restrict__ h16,  // [B][512][32] f16x2
    const float* __restrict__ tree,    // [128][512]
    const float* __restrict__ W3, const float* __restrict__ b3,
    const float* __restrict__ W4,
    unsigned long long* __restrict__ yfix)
{
    const int id   = blockIdx.x;          // 0..511
    const int xcd  = id & 7;
    const int ng   = (id >> 3) & 15;      // nodes ng*8 .. ng*8+7
    const int bq   = id >> 7;             // 0..3
    const int b    = bq * 8 + xcd;        // same XCD as K1's writers of b
    const int tid  = threadIdx.x;
    const int w    = tid >> 6;            // wave 0..7
    const int lane = tid & 63;
    const int g2   = lane >> 4;           // leaf-group 0..3
    const int p2   = lane & 15;           // pair-pair (channels 4*p2..4*p2+3)

    __shared__ unsigned smask[512];
    __shared__ float sred[8][8][64];
    __shared__ float sagg[8][64];
    __shared__ float sm[128];
    __shared__ float spart[8][64];

    // ---- per-leaf masks (thread owns leaf tid; coalesced) ----
    {
        unsigned bits = 0;
        const float* tp = tree + (size_t)(ng * 8) * 512 + tid;
        #pragma unroll
        for (int n = 0; n < 8; ++n)
            if (tp[(size_t)n * 512] > 0.5f) bits |= (1u << n);
        smask[tid] = bits;
    }
    __syncthreads();

    // ---- packed max-agg, dwordx2 loads: wave w owns leaves w*64..+63 ----
    unsigned accL[8], accH[8];
    #pragma unroll
    for (int n = 0; n < 8; ++n) { accL[n] = 0u; accH[n] = 0u; }  // h>=0 exact

    const uint2* hb = (const uint2*)(h16 + (size_t)b * 16384
                                     + (size_t)(w * 64 + g2) * 32 + 2 * p2);
    const unsigned* mp = &smask[w * 64 + g2];
    #pragma unroll 16
    for (int j = 0; j < 16; ++j) {
        const uint2 hv = hb[(size_t)j * 64];     // 4 f16 ch (8B, local L2)
        const unsigned mb = mp[4 * j];           // LDS b32 broadcast
        #pragma unroll
        for (int n = 0; n < 8; ++n) {
            const int sel = (int)(mb << (31 - n)) >> 31;   // bit n -> 0 / ~0
            accL[n] = pk_max_f16(accL[n], hv.x & (unsigned)sel);
            accH[n] = pk_max_f16(accH[n], hv.y & (unsigned)sel);
        }
    }
    // combine the 4 leaf-groups (lanes differing in bits 4,5)
    #pragma unroll
    for (int n = 0; n < 8; ++n) {
        accL[n] = pk_max_f16(accL[n], (unsigned)__shfl_xor((int)accL[n], 16));
        accH[n] = pk_max_f16(accH[n], (unsigned)__shfl_xor((int)accH[n], 16));
        accL[n] = pk_max_f16(accL[n], (unsigned)__shfl_xor((int)accL[n], 32));
        accH[n] = pk_max_f16(accH[n], (unsigned)__shfl_xor((int)accH[n], 32));
    }
    if (g2 == 0) {
        #pragma unroll
        for (int n = 0; n < 8; ++n) {
            const __half2 lo = *(const __half2*)&accL[n];
            const __half2 hi = *(const __half2*)&accH[n];
            *(float2*)&sred[w][n][4 * p2] =
                make_float2(__low2float(lo), __high2float(lo));
            *(float2*)&sred[w][n][4 * p2 + 2] =
                make_float2(__low2float(hi), __high2float(hi));
        }
    }
    __syncthreads();

    {   // combine 8 waves: tid covers (n=tid>>6, c=tid&63)
        const int n = tid >> 6, c = tid & 63;
        float v = sred[0][n][c];
        #pragma unroll
        for (int ww = 1; ww < 8; ++ww) v = fmaxf(v, sred[ww][n][c]);
        sagg[n][c] = v;
    }
    __syncthreads();

    // ---- f_macro ----
    if (tid < 128) {
        const int n = tid >> 4, jj = tid & 15;
        float a = b3[jj];
        #pragma unroll
        for (int c2 = 0; c2 < 64; ++c2)
            a += sagg[n][c2] * W3[c2 * 16 + jj];
        sm[tid] = fmaxf(a, 0.f);
    }
    __syncthreads();

    // ---- W4 slice ----
    {
        float a = 0.f;
        const float* w4p = W4 + (size_t)(ng * 128 + w * 16) * 64 + lane;
        #pragma unroll
        for (int k2 = 0; k2 < 16; ++k2)
            a += sm[w * 16 + k2] * w4p[(size_t)k2 * 64];
        spart[w][lane] = a;
    }
    __syncthreads();
    if (tid < 64) {
        float v = 0.f;
        #pragma unroll
        for (int ww = 0; ww < 8; ++ww) v += spart[ww][tid];
        // Q32.32: integer add is associative -> deterministic
        const long long q = llrintf(v * 4294967296.0f);
        atomicAdd(&yfix[(size_t)b * 64 + tid], (unsigned long long)q);
    }
}

// yfix -> y = relu(.+b4); BatchNorm (batch stats over B=32); @W5+b5.
__global__ __launch_bounds__(1024) void k_bn_out(
    const unsigned long long* __restrict__ yfix, const float* __restrict__ b4,
    const float* __restrict__ gamma, const float* __restrict__ beta,
    const float* __restrict__ W5, const float* __restrict__ b5,
    float* __restrict__ out)
{
    const int tid = threadIdx.x;
    __shared__ float sy[32 * 64];
    __shared__ float smean[64], sscale[64], sbeta[64];

    #pragma unroll
    for (int idx = tid; idx < 2048; idx += 1024) {
        const long long v = (long long)yfix[idx];
        sy[idx] = fmaxf((float)v * (1.0f / 4294967296.0f) + b4[idx & 63], 0.f);
    }
    __syncthreads();
    if (tid < 64) {
        float s1 = 0.f, s2 = 0.f;
        #pragma unroll
        for (int b = 0; b < 32; ++b) {
            const float v = sy[b * 64 + tid];
            s1 += v; s2 += v * v;
        }
        const float mean = s1 * (1.f / 32.f);
        const float var  = s2 * (1.f / 32.f) - mean * mean;  // biased, torch BN
        smean[tid]  = mean;
        sscale[tid] = gamma[tid] * rsqrtf(var + 1e-5f);
        sbeta[tid]  = beta[tid];
    }
    __syncthreads();
    if (tid < 320) {
        const int b = tid / 10, q = tid % 10;
        float acc = b5[q];
        #pragma unroll
        for (int o = 0; o < 64; ++o)
            acc += ((sy[b * 64 + o] - smean[o]) * sscale[o] + sbeta[o])
                   * W5[o * 10 + q];
        out[b * 10 + q] = acc;
    }
}

extern "C" void kernel_launch(void* const* d_in, const int* in_sizes, int n_in,
                              void* d_out, int out_size, void* d_ws, size_t ws_size,
                              hipStream_t stream) {
    const float* x     = (const float*)d_in[0];
    const float* tree  = (const float*)d_in[1];
    const float* W1    = (const float*)d_in[2];
    const float* b1    = (const float*)d_in[3];
    const float* W2    = (const float*)d_in[4];
    const float* b2    = (const float*)d_in[5];
    const float* W3    = (const float*)d_in[6];
    const float* b3    = (const float*)d_in[7];
    const float* W4    = (const float*)d_in[8];
    const float* b4    = (const float*)d_in[9];
    const float* gamma = (const float*)d_in[10];
    const float* beta  = (const float*)d_in[11];
    const float* W5    = (const float*)d_in[12];
    const float* b5    = (const float*)d_in[13];
    float* out = (float*)d_out;

    unsigned*           h16  = (unsigned*)d_ws;                       // 2 MB
    unsigned long long* yfix = (unsigned long long*)(h16 + 16384 * 32); // 16 KB

    k_micro   <<<512,  256, 0, stream>>>(x, W1, b1, W2, b2, h16, yfix);
    k_agg_part<<<512,  512, 0, stream>>>(h16, tree, W3, b3, W4, yfix);
    k_bn_out  <<<1,   1024, 0, stream>>>(yfix, b4, gamma, beta, W5, b5, out);
}